// Round 7
// baseline (500.334 us; speedup 1.0000x reference)
//
#include <hip/hip_runtime.h>
#include <cstdint>
#include <cstddef>

#define BB 64
#define HH 168
#define NN 512
#define FF 8
#define UL 128   // lstm units
#define GD 512   // gate dim (4*UL)

__device__ __forceinline__ float frcp(float x){ return __builtin_amdgcn_rcpf(x); }
__device__ __forceinline__ void pin4(float4 &v){
  asm volatile("" : "+v"(v.x), "+v"(v.y), "+v"(v.z), "+v"(v.w));
}

// ---------------- summaries: partial sums over half the H axis ----------------
__global__ __launch_bounds__(256) void k_sum(const float* __restrict__ in, float* __restrict__ ps){
  int bid = blockIdx.x;
  int b = bid>>2, nh = (bid>>1)&1, hh = bid&1;
  int n = nh*256 + threadIdx.x;
  int h0 = hh*84;
  const float* p = in + ((size_t)(b*HH + h0)*NN + n)*FF;
  float s1=0.f,s2=0.f,s3=0.f,s4=0.f,st=0.f;
  #pragma unroll 4
  for(int h=0;h<84;++h){
    float x = p[(size_t)h*NN*FF];
    float hc = (float)(h+h0) - 83.5f;
    s1 += x;
    float x2 = x*x;
    s2 += x2;
    s3 += x2*x;
    s4 += x2*x2;
    st += hc*x;
  }
  float* o = ps + ((size_t)((b*NN+n)*2 + hh))*8;
  o[0]=s1; o[1]=s2; o[2]=s3; o[3]=s4; o[4]=st;
}

__global__ __launch_bounds__(256) void k_sumc(const float* __restrict__ ps, float* __restrict__ nf){
  int idx = blockIdx.x*256 + threadIdx.x;
  const float* a = ps + (size_t)idx*16;
  const float* c2 = a + 8;
  float s1 = a[0]+c2[0], s2 = a[1]+c2[1], s3 = a[2]+c2[2], s4 = a[3]+c2[3], st = a[4]+c2[4];
  float s1h = c2[0], s2h = c2[1];
  const float iH = 1.0f/168.0f, iHh = 1.0f/84.0f;
  float mean = s1*iH, meanh = s1h*iHh;
  float ex2 = s2*iH, ex3 = s3*iH, ex4 = s4*iH;
  float m2 = ex2 - mean*mean;
  float m3 = ex3 - 3.0f*mean*ex2 + 2.0f*mean*mean*mean;
  float m4 = ex4 - 4.0f*mean*ex3 + 6.0f*mean*mean*ex2 - 3.0f*mean*mean*mean*mean;
  m2 = fmaxf(m2, 0.0f);
  float stdf = sqrtf(m2);
  float m2h = fmaxf(s2h*iHh - meanh*meanh, 0.0f);
  float stdh = sqrtf(m2h);
  float denom = m2*stdf;
  float skew = denom > 0.0f ? m3/denom : 0.0f;
  float kurt = m2 > 0.0f ? (m4/(m2*m2) - 3.0f) : 0.0f;
  float slope = st * (1.0f/395122.0f);
  float* o = nf + (size_t)idx*7;
  o[0]=mean; o[1]=meanh; o[2]=stdf; o[3]=stdh; o[4]=skew; o[5]=kurt; o[6]=slope;
}

// ---------------- GCN layer 1 ----------------
__global__ __launch_bounds__(256) void k_gcn1(const float* __restrict__ nf, const float* __restrict__ adj,
        const float* __restrict__ w1, const float* __restrict__ b1, float* __restrict__ h1){
  __shared__ float t_s[NN*32];
  __shared__ float adj_s[128*68];
  int b = blockIdx.x>>2, n0 = (blockIdx.x&3)*128;
  int tid = threadIdx.x;
  {
    int c = tid&31;
    float w1c[7];
    #pragma unroll
    for(int k=0;k<7;++k) w1c[k] = w1[k*32+c];
    for(int idx=tid; idx<NN*32; idx+=256){
      int m = idx>>5;
      const float* nfp = nf + (size_t)(b*NN+m)*7;
      float acc = 0.f;
      #pragma unroll
      for(int k=0;k<7;++k) acc += nfp[k]*w1c[k];
      t_s[idx] = acc;
    }
  }
  int c2 = tid&15, nl = tid>>4;
  float acc[8][2];
  #pragma unroll
  for(int j=0;j<8;++j){acc[j][0]=0.f;acc[j][1]=0.f;}
  for(int mt=0; mt<8; ++mt){
    __syncthreads();
    for(int idx=tid; idx<128*64; idx+=256){
      int r = idx>>6, cc = idx&63;
      adj_s[r*68+cc] = adj[(size_t)(n0+r)*NN + mt*64 + cc];
    }
    __syncthreads();
    for(int mm=0; mm<64; mm+=4){
      float2 tv[4];
      #pragma unroll
      for(int q=0;q<4;++q) tv[q] = *(const float2*)&t_s[(mt*64+mm+q)*32 + 2*c2];
      #pragma unroll
      for(int j=0;j<8;++j){
        float4 a4 = *(const float4*)&adj_s[(nl+16*j)*68 + mm];
        acc[j][0] += a4.x*tv[0].x + a4.y*tv[1].x + a4.z*tv[2].x + a4.w*tv[3].x;
        acc[j][1] += a4.x*tv[0].y + a4.y*tv[1].y + a4.z*tv[2].y + a4.w*tv[3].y;
      }
    }
  }
  float bb0 = b1[2*c2], bb1 = b1[2*c2+1];
  #pragma unroll
  for(int j=0;j<8;++j){
    int n = n0 + nl + 16*j;
    float2 v;
    v.x = fmaxf(acc[j][0]+bb0, 0.0f);
    v.y = fmaxf(acc[j][1]+bb1, 0.0f);
    *(float2*)&h1[(size_t)(b*NN+n)*32 + 2*c2] = v;
  }
}

// ---------------- GCN layer 2 ----------------
__global__ __launch_bounds__(256) void k_gcn2(const float* __restrict__ h1, const float* __restrict__ adj,
        const float* __restrict__ w2, const float* __restrict__ b2, float* __restrict__ g){
  __shared__ float t_s[NN*16];
  __shared__ float adj_s[128*68];
  int b = blockIdx.x>>2, n0 = (blockIdx.x&3)*128;
  int tid = threadIdx.x;
  {
    int jh = tid&7;
    float w2c0[32], w2c1[32];
    #pragma unroll
    for(int c=0;c<32;++c){ w2c0[c] = w2[c*16+2*jh]; w2c1[c] = w2[c*16+2*jh+1]; }
    for(int idx=tid; idx<NN*8; idx+=256){
      int m = idx>>3;
      const float4* hp = (const float4*)(h1 + (size_t)(b*NN+m)*32);
      float a0=0.f, a1=0.f;
      #pragma unroll
      for(int q=0;q<8;++q){
        float4 hv = hp[q];
        a0 += hv.x*w2c0[4*q] + hv.y*w2c0[4*q+1] + hv.z*w2c0[4*q+2] + hv.w*w2c0[4*q+3];
        a1 += hv.x*w2c1[4*q] + hv.y*w2c1[4*q+1] + hv.z*w2c1[4*q+2] + hv.w*w2c1[4*q+3];
      }
      t_s[m*16+2*jh] = a0;
      t_s[m*16+2*jh+1] = a1;
    }
  }
  int j = tid&15, nl = tid>>4;
  float acc[8];
  #pragma unroll
  for(int q=0;q<8;++q) acc[q]=0.f;
  for(int mt=0; mt<8; ++mt){
    __syncthreads();
    for(int idx=tid; idx<128*64; idx+=256){
      int r = idx>>6, cc = idx&63;
      adj_s[r*68+cc] = adj[(size_t)(n0+r)*NN + mt*64 + cc];
    }
    __syncthreads();
    for(int mm=0; mm<64; mm+=4){
      float tv[4];
      #pragma unroll
      for(int q=0;q<4;++q) tv[q] = t_s[(mt*64+mm+q)*16 + j];
      #pragma unroll
      for(int q=0;q<8;++q){
        float4 a4 = *(const float4*)&adj_s[(nl+16*q)*68 + mm];
        acc[q] += a4.x*tv[0] + a4.y*tv[1] + a4.z*tv[2] + a4.w*tv[3];
      }
    }
  }
  float bbj = b2[j];
  #pragma unroll
  for(int q=0;q<8;++q){
    int n = n0 + nl + 16*q;
    g[(size_t)(b*NN+n)*16 + j] = fmaxf(acc[q]+bbj, 0.0f);
  }
}

// ---------------- conv1 -> pool -> conv2 ----------------
__global__ __launch_bounds__(256) void k_conv(const float* __restrict__ g, const float* __restrict__ wc1,
        const float* __restrict__ bc1, const float* __restrict__ wc2, const float* __restrict__ bc2,
        float* __restrict__ feat){
  __shared__ float g_s[NN*16];
  __shared__ float w1_s[3*NN*4];
  __shared__ float c1p[4][4][16];
  __shared__ float c1_s[4][16];
  __shared__ float p_s[4][8];
  int b = blockIdx.x, tid = threadIdx.x;
  for(int idx=tid; idx<NN*16; idx+=256) g_s[idx] = g[(size_t)b*NN*16 + idx];
  for(int idx=tid; idx<3*NN*4; idx+=256) w1_s[idx] = wc1[idx];
  __syncthreads();
  {
    int q = tid>>6, p = tid&63, o = p>>4, x = p&15;
    int c0 = q*128;
    float acc = 0.f;
    #pragma unroll
    for(int k=0;k<3;++k){
      int xx = x + k - 1;
      if(xx>=0 && xx<16){
        #pragma unroll 4
        for(int c=c0;c<c0+128;++c) acc += g_s[c*16+xx]*w1_s[(k*NN+c)*4+o];
      }
    }
    c1p[q][o][x] = acc;
  }
  __syncthreads();
  if(tid<64){
    int o = tid>>4, x = tid&15;
    c1_s[o][x] = c1p[0][o][x]+c1p[1][o][x]+c1p[2][o][x]+c1p[3][o][x] + bc1[o];
  }
  __syncthreads();
  if(tid<32){
    int oo = tid>>3, xp = tid&7;
    float pv = 0.5f*(c1_s[oo][2*xp]+c1_s[oo][2*xp+1]);
    p_s[oo][xp] = pv;
    feat[b*192 + 32 + oo*8 + xp] = pv;
  }
  __syncthreads();
  if(tid<32){
    int oo = tid>>3, x2 = tid&7;
    float a2 = bc2[oo];
    #pragma unroll
    for(int k=0;k<3;++k){
      int xx = x2 + k - 1;
      if(xx>=0 && xx<8){
        #pragma unroll
        for(int c=0;c<4;++c) a2 += p_s[c][xx]*wc2[(k*4+c)*4+oo];
      }
    }
    feat[b*192 + oo*8 + x2] = a2;
  }
}

// ---------------- xk1: zin = inputs[:,:,0,:] @ k1 + b1 (non-recurrent) ----------------
__global__ __launch_bounds__(256) void k_xk1(const float* __restrict__ in, const float* __restrict__ k1,
        const float* __restrict__ b1, float* __restrict__ zin){
  __shared__ float x_s[21*FF];
  int b = blockIdx.x>>3, t0 = (blockIdx.x&7)*21;
  int tid = threadIdx.x;
  for(int idx=tid; idx<21*FF; idx+=256)
    x_s[idx] = in[(size_t)(b*HH + t0 + (idx>>3))*NN*FF + (idx&7)];
  __syncthreads();
  float acc0[21], acc1[21];
  #pragma unroll
  for(int q=0;q<21;++q){acc0[q]=0.f;acc1[q]=0.f;}
  #pragma unroll
  for(int j=0;j<FF;++j){
    float kv0 = k1[j*GD + tid];
    float kv1 = k1[j*GD + tid + 256];
    #pragma unroll
    for(int q=0;q<21;++q){
      float xv = x_s[q*FF + j];
      acc0[q] += xv*kv0;
      acc1[q] += xv*kv1;
    }
  }
  float bb0 = b1[tid], bb1 = b1[tid+256];
  #pragma unroll
  for(int q=0;q<21;++q){
    zin[((size_t)b*HH + t0 + q)*GD + tid]       = acc0[q] + bb0;
    zin[((size_t)b*HH + t0 + q)*GD + tid + 256] = acc1[q] + bb1;
  }
}

// ---------------- zin2 = l1 @ k2 + b2 ----------------
__global__ __launch_bounds__(256) void k_zin2(const float* __restrict__ l1, const float* __restrict__ k2,
        const float* __restrict__ b2, float* __restrict__ zin){
  __shared__ float l_s[21*UL];
  int b = blockIdx.x>>3, t0 = (blockIdx.x&7)*21;
  int tid = threadIdx.x;
  for(int idx=tid; idx<21*UL; idx+=256)
    l_s[idx] = l1[((size_t)b*HH + t0 + (idx>>7))*UL + (idx&127)];
  __syncthreads();
  float acc0[21], acc1[21];
  #pragma unroll
  for(int q=0;q<21;++q){acc0[q]=0.f;acc1[q]=0.f;}
  for(int j=0;j<UL;j+=4){
    float kv00=k2[j*GD+tid],     kv01=k2[(j+1)*GD+tid],     kv02=k2[(j+2)*GD+tid],     kv03=k2[(j+3)*GD+tid];
    float kv10=k2[j*GD+tid+256], kv11=k2[(j+1)*GD+tid+256], kv12=k2[(j+2)*GD+tid+256], kv13=k2[(j+3)*GD+tid+256];
    #pragma unroll
    for(int q=0;q<21;++q){
      float4 lv = *(const float4*)&l_s[q*UL + j];
      acc0[q] += lv.x*kv00 + lv.y*kv01 + lv.z*kv02 + lv.w*kv03;
      acc1[q] += lv.x*kv10 + lv.y*kv11 + lv.z*kv12 + lv.w*kv13;
    }
  }
  float bb0 = b2[tid], bb1 = b2[tid+256];
  #pragma unroll
  for(int q=0;q<21;++q){
    zin[((size_t)b*HH + t0 + q)*GD + tid]       = acc0[q] + bb0;
    zin[((size_t)b*HH + t0 + q)*GD + tid + 256] = acc1[q] + bb1;
  }
}

// ---------------- LSTM recurrence: 1024 thr, split-K=8, PINNED register weights ----------------
// lane bits: [2:0]=ks (K slice h[16ks..16ks+15]), [3]=b3, [5:4]=gate; wave w.
// thread's quad cols: cbase = gate*128 + w*8 + b3*4; after reduce lane holds col = cbase + (l&3).
// 64 weight floats/thread pinned live via asm; budget 128 VGPR (4 waves/SIMD) accommodates ~95.
__global__ __launch_bounds__(1024,4) __attribute__((amdgpu_waves_per_eu(4,4)))
void k_rec(const float* __restrict__ zin, const float* __restrict__ rk,
           float* __restrict__ oseq, float* __restrict__ olast, int writeSeq){
  __shared__ float hbuf[2][8*20];   // slice ks at [ks*20 .. ks*20+15], conflict-free, 16B-aligned
  int b = blockIdx.x, tid = threadIdx.x;
  int w = tid>>6, l = tid&63;
  int gate = l>>4;
  int ks = l&7;
  int b3 = (l>>3)&1;
  int cbase = gate*128 + w*8 + b3*4;
  int col = cbase + (l&3);
  int u = w*8 + b3*4 + (l&3);
  bool q0 = (l&1)!=0, q1 = (l&2)!=0;
  bool wr = (gate==0) && ((l&4)==0);

  float4 w4[16];
  #pragma unroll
  for(int k=0;k<16;++k)
    w4[k] = *(const float4*)(rk + (size_t)(ks*16+k)*GD + cbase);
  #pragma unroll
  for(int k=0;k<16;++k) pin4(w4[k]);   // force VGPR residency (defeat MachineLICM refusal/remat)

  bool isg = (gate==2);
  float Ac = isg?1.f:0.f, Bc = isg?-2.f:1.f, Sc = isg?2.f:-1.f;

  if(tid<UL) hbuf[0][(tid>>4)*20 + (tid&15)] = 0.0f;
  float c = 0.0f;
  float zc = zin[(size_t)b*HH*GD + col];
  __syncthreads();

  int cur = 0;
  #pragma unroll 1
  for(int t=0;t<HH;++t){
    float nz = 0.f;
    if(t+1<HH) nz = zin[((size_t)b*HH + t+1)*GD + col];   // prefetch next step
    const float4* hq = (const float4*)&hbuf[cur][ks*20];
    float p0=0.f,p1=0.f,p2=0.f,p3=0.f;
    #pragma unroll
    for(int j=0;j<4;++j){
      float4 hv = hq[j];
      p0 += hv.x*w4[4*j].x + hv.y*w4[4*j+1].x + hv.z*w4[4*j+2].x + hv.w*w4[4*j+3].x;
      p1 += hv.x*w4[4*j].y + hv.y*w4[4*j+1].y + hv.z*w4[4*j+2].y + hv.w*w4[4*j+3].y;
      p2 += hv.x*w4[4*j].z + hv.y*w4[4*j+1].z + hv.z*w4[4*j+2].z + hv.w*w4[4*j+3].z;
      p3 += hv.x*w4[4*j].w + hv.y*w4[4*j+1].w + hv.z*w4[4*j+2].w + hv.w*w4[4*j+3].w;
    }
    // fold ks and ks^4 (identical col quads)
    p0 += __shfl_xor(p0,4); p1 += __shfl_xor(p1,4);
    p2 += __shfl_xor(p2,4); p3 += __shfl_xor(p3,4);
    // 4-lane transpose-reduce (R3-validated): lane ends with col = cbase + (l&3)
    float send0 = q0 ? p0 : p1;
    float send1 = q0 ? p2 : p3;
    float r0 = __shfl_xor(send0, 1);
    float r1 = __shfl_xor(send1, 1);
    float s0 = (q0 ? p1 : p0) + r0;
    float s1v = (q0 ? p3 : p2) + r1;
    float send2 = q1 ? s0 : s1v;
    float r2 = __shfl_xor(send2, 2);
    float z = zc + (q1 ? s1v : s0) + r2;
    // activation (gates 0,1,3 sigmoid; gate 2 tanh)
    float act = Ac + Bc*frcp(1.0f + __expf(Sc*z));
    // gate exchange (R4-validated): xor16 flips gate bit0, xor32 flips gate bit1
    float r16 = __shfl_xor(act, 16);
    float r32 = __shfl_xor(act, 32);
    float r48 = __shfl_xor(r16, 32);
    float ia = gate==0?act : gate==1?r16 : gate==2?r32 : r48;
    float fa = gate==0?r16 : gate==1?act : gate==2?r48 : r32;
    float ga = gate==0?r32 : gate==1?r48 : gate==2?act : r16;
    float oa = gate==0?r48 : gate==1?r32 : gate==2?r16 : act;
    c = fa*c + ia*ga;
    float th = 1.0f - 2.0f*frcp(1.0f + __expf(2.0f*c));
    float hn = oa*th;
    if(wr){
      hbuf[cur^1][(u>>4)*20 + (u&15)] = hn;
      if(writeSeq) oseq[((size_t)b*HH + t)*UL + u] = hn;
      else if(t==HH-1) olast[b*192 + 64 + u] = hn;
    }
    __syncthreads();
    cur ^= 1;
    zc = nz;
  }
}

// ---------------- final dense ----------------
__global__ __launch_bounds__(256) void k_out(const float* __restrict__ feat, const float* __restrict__ wo,
        const float* __restrict__ bo, float* __restrict__ out){
  int idx = blockIdx.x*256 + threadIdx.x;
  if(idx >= BB*24) return;
  int b = idx/24, p = idx - b*24;
  float a0 = bo[p], a1 = 0.f, a2 = 0.f, a3 = 0.f;
  const float* f = feat + b*192;
  for(int k=0;k<192;k+=4){
    a0 += f[k]*wo[k*24+p];
    a1 += f[k+1]*wo[(k+1)*24+p];
    a2 += f[k+2]*wo[(k+2)*24+p];
    a3 += f[k+3]*wo[(k+3)*24+p];
  }
  out[idx] = (a0+a1)+(a2+a3);
}

extern "C" void kernel_launch(void* const* d_in, const int* in_sizes, int n_in,
                              void* d_out, int out_size, void* d_ws, size_t ws_size,
                              hipStream_t stream){
  const float* inp = (const float*)d_in[0];
  const float* adj = (const float*)d_in[1];
  const float* w1  = (const float*)d_in[2];
  const float* b1  = (const float*)d_in[3];
  const float* w2  = (const float*)d_in[4];
  const float* b2  = (const float*)d_in[5];
  const float* wc1 = (const float*)d_in[6];
  const float* bc1 = (const float*)d_in[7];
  const float* wc2 = (const float*)d_in[8];
  const float* bc2 = (const float*)d_in[9];
  const float* k1  = (const float*)d_in[10];
  const float* rk1 = (const float*)d_in[11];
  const float* bl1 = (const float*)d_in[12];
  const float* k2  = (const float*)d_in[13];
  const float* rk2 = (const float*)d_in[14];
  const float* bl2 = (const float*)d_in[15];
  const float* wo  = (const float*)d_in[16];
  const float* bo  = (const float*)d_in[17];
  float* out = (float*)d_out;
  float* ws = (float*)d_ws;

  float* ps   = ws;                 // 524288
  float* nf   = ps + 524288;        // 229376
  float* h1   = nf + 229376;        // 1048576
  float* g    = h1 + 1048576;       // 524288
  float* feat = g  + 524288;        // 12288
  float* l1   = feat + 12288;       // 1376256
  float* zin  = l1 + 1376256;       // 5505024 (shared by zin1 and zin2, sequential use)

  k_sum  <<<dim3(256), dim3(256), 0, stream>>>(inp, ps);
  k_sumc <<<dim3(128), dim3(256), 0, stream>>>(ps, nf);
  k_gcn1 <<<dim3(256), dim3(256), 0, stream>>>(nf, adj, w1, b1, h1);
  k_gcn2 <<<dim3(256), dim3(256), 0, stream>>>(h1, adj, w2, b2, g);
  k_conv <<<dim3(64),  dim3(256), 0, stream>>>(g, wc1, bc1, wc2, bc2, feat);
  k_xk1  <<<dim3(512), dim3(256), 0, stream>>>(inp, k1, bl1, zin);
  k_rec  <<<dim3(64),  dim3(1024),0, stream>>>(zin, rk1, l1, feat, 1);
  k_zin2 <<<dim3(512), dim3(256), 0, stream>>>(l1, k2, bl2, zin);
  k_rec  <<<dim3(64),  dim3(1024),0, stream>>>(zin, rk2, l1, feat, 0);
  k_out  <<<dim3(6),   dim3(256), 0, stream>>>(feat, wo, bo, out);
}

// Round 8
// 443.682 us; speedup vs baseline: 1.1277x; 1.1277x over previous
//
#include <hip/hip_runtime.h>
#include <cstdint>
#include <cstddef>

#define BB 64
#define HH 168
#define NN 512
#define FF 8
#define UL 128   // lstm units
#define GD 512   // gate dim (4*UL)

__device__ __forceinline__ float frcp(float x){ return __builtin_amdgcn_rcpf(x); }
__device__ __forceinline__ void pin4(float4 &v){
  asm volatile("" : "+v"(v.x), "+v"(v.y), "+v"(v.z), "+v"(v.w));
}

// ---------------- summaries: partial sums over half the H axis ----------------
__global__ __launch_bounds__(256) void k_sum(const float* __restrict__ in, float* __restrict__ ps){
  int bid = blockIdx.x;
  int b = bid>>2, nh = (bid>>1)&1, hh = bid&1;
  int n = nh*256 + threadIdx.x;
  int h0 = hh*84;
  const float* p = in + ((size_t)(b*HH + h0)*NN + n)*FF;
  float s1=0.f,s2=0.f,s3=0.f,s4=0.f,st=0.f;
  #pragma unroll 4
  for(int h=0;h<84;++h){
    float x = p[(size_t)h*NN*FF];
    float hc = (float)(h+h0) - 83.5f;
    s1 += x;
    float x2 = x*x;
    s2 += x2;
    s3 += x2*x;
    s4 += x2*x2;
    st += hc*x;
  }
  float* o = ps + ((size_t)((b*NN+n)*2 + hh))*8;
  o[0]=s1; o[1]=s2; o[2]=s3; o[3]=s4; o[4]=st;
}

__global__ __launch_bounds__(256) void k_sumc(const float* __restrict__ ps, float* __restrict__ nf){
  int idx = blockIdx.x*256 + threadIdx.x;
  const float* a = ps + (size_t)idx*16;
  const float* c2 = a + 8;
  float s1 = a[0]+c2[0], s2 = a[1]+c2[1], s3 = a[2]+c2[2], s4 = a[3]+c2[3], st = a[4]+c2[4];
  float s1h = c2[0], s2h = c2[1];
  const float iH = 1.0f/168.0f, iHh = 1.0f/84.0f;
  float mean = s1*iH, meanh = s1h*iHh;
  float ex2 = s2*iH, ex3 = s3*iH, ex4 = s4*iH;
  float m2 = ex2 - mean*mean;
  float m3 = ex3 - 3.0f*mean*ex2 + 2.0f*mean*mean*mean;
  float m4 = ex4 - 4.0f*mean*ex3 + 6.0f*mean*mean*ex2 - 3.0f*mean*mean*mean*mean;
  m2 = fmaxf(m2, 0.0f);
  float stdf = sqrtf(m2);
  float m2h = fmaxf(s2h*iHh - meanh*meanh, 0.0f);
  float stdh = sqrtf(m2h);
  float denom = m2*stdf;
  float skew = denom > 0.0f ? m3/denom : 0.0f;
  float kurt = m2 > 0.0f ? (m4/(m2*m2) - 3.0f) : 0.0f;
  float slope = st * (1.0f/395122.0f);
  float* o = nf + (size_t)idx*7;
  o[0]=mean; o[1]=meanh; o[2]=stdf; o[3]=stdh; o[4]=skew; o[5]=kurt; o[6]=slope;
}

// ---------------- GCN layer 1 ----------------
__global__ __launch_bounds__(256) void k_gcn1(const float* __restrict__ nf, const float* __restrict__ adj,
        const float* __restrict__ w1, const float* __restrict__ b1, float* __restrict__ h1){
  __shared__ float t_s[NN*32];
  __shared__ float adj_s[128*68];
  int b = blockIdx.x>>2, n0 = (blockIdx.x&3)*128;
  int tid = threadIdx.x;
  {
    int c = tid&31;
    float w1c[7];
    #pragma unroll
    for(int k=0;k<7;++k) w1c[k] = w1[k*32+c];
    for(int idx=tid; idx<NN*32; idx+=256){
      int m = idx>>5;
      const float* nfp = nf + (size_t)(b*NN+m)*7;
      float acc = 0.f;
      #pragma unroll
      for(int k=0;k<7;++k) acc += nfp[k]*w1c[k];
      t_s[idx] = acc;
    }
  }
  int c2 = tid&15, nl = tid>>4;
  float acc[8][2];
  #pragma unroll
  for(int j=0;j<8;++j){acc[j][0]=0.f;acc[j][1]=0.f;}
  for(int mt=0; mt<8; ++mt){
    __syncthreads();
    for(int idx=tid; idx<128*64; idx+=256){
      int r = idx>>6, cc = idx&63;
      adj_s[r*68+cc] = adj[(size_t)(n0+r)*NN + mt*64 + cc];
    }
    __syncthreads();
    for(int mm=0; mm<64; mm+=4){
      float2 tv[4];
      #pragma unroll
      for(int q=0;q<4;++q) tv[q] = *(const float2*)&t_s[(mt*64+mm+q)*32 + 2*c2];
      #pragma unroll
      for(int j=0;j<8;++j){
        float4 a4 = *(const float4*)&adj_s[(nl+16*j)*68 + mm];
        acc[j][0] += a4.x*tv[0].x + a4.y*tv[1].x + a4.z*tv[2].x + a4.w*tv[3].x;
        acc[j][1] += a4.x*tv[0].y + a4.y*tv[1].y + a4.z*tv[2].y + a4.w*tv[3].y;
      }
    }
  }
  float bb0 = b1[2*c2], bb1 = b1[2*c2+1];
  #pragma unroll
  for(int j=0;j<8;++j){
    int n = n0 + nl + 16*j;
    float2 v;
    v.x = fmaxf(acc[j][0]+bb0, 0.0f);
    v.y = fmaxf(acc[j][1]+bb1, 0.0f);
    *(float2*)&h1[(size_t)(b*NN+n)*32 + 2*c2] = v;
  }
}

// ---------------- GCN layer 2 ----------------
__global__ __launch_bounds__(256) void k_gcn2(const float* __restrict__ h1, const float* __restrict__ adj,
        const float* __restrict__ w2, const float* __restrict__ b2, float* __restrict__ g){
  __shared__ float t_s[NN*16];
  __shared__ float adj_s[128*68];
  int b = blockIdx.x>>2, n0 = (blockIdx.x&3)*128;
  int tid = threadIdx.x;
  {
    int jh = tid&7;
    float w2c0[32], w2c1[32];
    #pragma unroll
    for(int c=0;c<32;++c){ w2c0[c] = w2[c*16+2*jh]; w2c1[c] = w2[c*16+2*jh+1]; }
    for(int idx=tid; idx<NN*8; idx+=256){
      int m = idx>>3;
      const float4* hp = (const float4*)(h1 + (size_t)(b*NN+m)*32);
      float a0=0.f, a1=0.f;
      #pragma unroll
      for(int q=0;q<8;++q){
        float4 hv = hp[q];
        a0 += hv.x*w2c0[4*q] + hv.y*w2c0[4*q+1] + hv.z*w2c0[4*q+2] + hv.w*w2c0[4*q+3];
        a1 += hv.x*w2c1[4*q] + hv.y*w2c1[4*q+1] + hv.z*w2c1[4*q+2] + hv.w*w2c1[4*q+3];
      }
      t_s[m*16+2*jh] = a0;
      t_s[m*16+2*jh+1] = a1;
    }
  }
  int j = tid&15, nl = tid>>4;
  float acc[8];
  #pragma unroll
  for(int q=0;q<8;++q) acc[q]=0.f;
  for(int mt=0; mt<8; ++mt){
    __syncthreads();
    for(int idx=tid; idx<128*64; idx+=256){
      int r = idx>>6, cc = idx&63;
      adj_s[r*68+cc] = adj[(size_t)(n0+r)*NN + mt*64 + cc];
    }
    __syncthreads();
    for(int mm=0; mm<64; mm+=4){
      float tv[4];
      #pragma unroll
      for(int q=0;q<4;++q) tv[q] = t_s[(mt*64+mm+q)*16 + j];
      #pragma unroll
      for(int q=0;q<8;++q){
        float4 a4 = *(const float4*)&adj_s[(nl+16*q)*68 + mm];
        acc[q] += a4.x*tv[0] + a4.y*tv[1] + a4.z*tv[2] + a4.w*tv[3];
      }
    }
  }
  float bbj = b2[j];
  #pragma unroll
  for(int q=0;q<8;++q){
    int n = n0 + nl + 16*q;
    g[(size_t)(b*NN+n)*16 + j] = fmaxf(acc[q]+bbj, 0.0f);
  }
}

// ---------------- conv1 -> pool -> conv2 ----------------
__global__ __launch_bounds__(256) void k_conv(const float* __restrict__ g, const float* __restrict__ wc1,
        const float* __restrict__ bc1, const float* __restrict__ wc2, const float* __restrict__ bc2,
        float* __restrict__ feat){
  __shared__ float g_s[NN*16];
  __shared__ float w1_s[3*NN*4];
  __shared__ float c1p[4][4][16];
  __shared__ float c1_s[4][16];
  __shared__ float p_s[4][8];
  int b = blockIdx.x, tid = threadIdx.x;
  for(int idx=tid; idx<NN*16; idx+=256) g_s[idx] = g[(size_t)b*NN*16 + idx];
  for(int idx=tid; idx<3*NN*4; idx+=256) w1_s[idx] = wc1[idx];
  __syncthreads();
  {
    int q = tid>>6, p = tid&63, o = p>>4, x = p&15;
    int c0 = q*128;
    float acc = 0.f;
    #pragma unroll
    for(int k=0;k<3;++k){
      int xx = x + k - 1;
      if(xx>=0 && xx<16){
        #pragma unroll 4
        for(int c=c0;c<c0+128;++c) acc += g_s[c*16+xx]*w1_s[(k*NN+c)*4+o];
      }
    }
    c1p[q][o][x] = acc;
  }
  __syncthreads();
  if(tid<64){
    int o = tid>>4, x = tid&15;
    c1_s[o][x] = c1p[0][o][x]+c1p[1][o][x]+c1p[2][o][x]+c1p[3][o][x] + bc1[o];
  }
  __syncthreads();
  if(tid<32){
    int oo = tid>>3, xp = tid&7;
    float pv = 0.5f*(c1_s[oo][2*xp]+c1_s[oo][2*xp+1]);
    p_s[oo][xp] = pv;
    feat[b*192 + 32 + oo*8 + xp] = pv;
  }
  __syncthreads();
  if(tid<32){
    int oo = tid>>3, x2 = tid&7;
    float a2 = bc2[oo];
    #pragma unroll
    for(int k=0;k<3;++k){
      int xx = x2 + k - 1;
      if(xx>=0 && xx<8){
        #pragma unroll
        for(int c=0;c<4;++c) a2 += p_s[c][xx]*wc2[(k*4+c)*4+oo];
      }
    }
    feat[b*192 + oo*8 + x2] = a2;
  }
}

// ---------------- xk1: zin = inputs[:,:,0,:] @ k1 + b1 (non-recurrent) ----------------
__global__ __launch_bounds__(256) void k_xk1(const float* __restrict__ in, const float* __restrict__ k1,
        const float* __restrict__ b1, float* __restrict__ zin){
  __shared__ float x_s[21*FF];
  int b = blockIdx.x>>3, t0 = (blockIdx.x&7)*21;
  int tid = threadIdx.x;
  for(int idx=tid; idx<21*FF; idx+=256)
    x_s[idx] = in[(size_t)(b*HH + t0 + (idx>>3))*NN*FF + (idx&7)];
  __syncthreads();
  float acc0[21], acc1[21];
  #pragma unroll
  for(int q=0;q<21;++q){acc0[q]=0.f;acc1[q]=0.f;}
  #pragma unroll
  for(int j=0;j<FF;++j){
    float kv0 = k1[j*GD + tid];
    float kv1 = k1[j*GD + tid + 256];
    #pragma unroll
    for(int q=0;q<21;++q){
      float xv = x_s[q*FF + j];
      acc0[q] += xv*kv0;
      acc1[q] += xv*kv1;
    }
  }
  float bb0 = b1[tid], bb1 = b1[tid+256];
  #pragma unroll
  for(int q=0;q<21;++q){
    zin[((size_t)b*HH + t0 + q)*GD + tid]       = acc0[q] + bb0;
    zin[((size_t)b*HH + t0 + q)*GD + tid + 256] = acc1[q] + bb1;
  }
}

// ---------------- zin2 = l1 @ k2 + b2 ----------------
__global__ __launch_bounds__(256) void k_zin2(const float* __restrict__ l1, const float* __restrict__ k2,
        const float* __restrict__ b2, float* __restrict__ zin){
  __shared__ float l_s[21*UL];
  int b = blockIdx.x>>3, t0 = (blockIdx.x&7)*21;
  int tid = threadIdx.x;
  for(int idx=tid; idx<21*UL; idx+=256)
    l_s[idx] = l1[((size_t)b*HH + t0 + (idx>>7))*UL + (idx&127)];
  __syncthreads();
  float acc0[21], acc1[21];
  #pragma unroll
  for(int q=0;q<21;++q){acc0[q]=0.f;acc1[q]=0.f;}
  for(int j=0;j<UL;j+=4){
    float kv00=k2[j*GD+tid],     kv01=k2[(j+1)*GD+tid],     kv02=k2[(j+2)*GD+tid],     kv03=k2[(j+3)*GD+tid];
    float kv10=k2[j*GD+tid+256], kv11=k2[(j+1)*GD+tid+256], kv12=k2[(j+2)*GD+tid+256], kv13=k2[(j+3)*GD+tid+256];
    #pragma unroll
    for(int q=0;q<21;++q){
      float4 lv = *(const float4*)&l_s[q*UL + j];
      acc0[q] += lv.x*kv00 + lv.y*kv01 + lv.z*kv02 + lv.w*kv03;
      acc1[q] += lv.x*kv10 + lv.y*kv11 + lv.z*kv12 + lv.w*kv13;
    }
  }
  float bb0 = b2[tid], bb1 = b2[tid+256];
  #pragma unroll
  for(int q=0;q<21;++q){
    zin[((size_t)b*HH + t0 + q)*GD + tid]       = acc0[q] + bb0;
    zin[((size_t)b*HH + t0 + q)*GD + tid + 256] = acc1[q] + bb1;
  }
}

// ---------------- LSTM recurrence: 512 thr, split-K=4 (R3 geometry), resident weights ----------------
// thread tid: q=tid&3 (h slice h[32q..32q+32)), grp=tid>>2 (cols 4grp..4grp+3); reduced z at col=tid.
// 128 weight floats/thread pinned; waves_per_eu(2,2) -> 256-VGPR budget (min=max stops allocator
// from targeting higher occupancy and spilling, which is what killed R5/R7).
__global__ __launch_bounds__(512) __attribute__((amdgpu_waves_per_eu(2,2)))
void k_rec(const float* __restrict__ zin, const float* __restrict__ rk,
           float* __restrict__ oseq, float* __restrict__ olast, int writeSeq){
  __shared__ float hbuf[2][4*36];   // slice q at [q*36 .. q*36+31], stride-36 conflict-free (R3)
  __shared__ float a_s[UL*4];       // [unit][gate] -> cell update reads one b128
  int b = blockIdx.x, tid = threadIdx.x;
  int q = tid&3, grp = tid>>2;
  int gate = tid>>7;                 // 0..3, wave-uniform
  int u = tid&127;
  bool q0 = (tid&1)!=0, q1 = (tid&2)!=0;

  // weights: w4[k] = rk[(q*32+k)][4grp..4grp+3]  (R3-validated layout)
  float4 w4[32];
  {
    const float4* rkp = (const float4*)rk;
    #pragma unroll
    for(int k=0;k<32;++k) w4[k] = rkp[(size_t)(q*32+k)*(GD/4) + grp];
    #pragma unroll
    for(int k=0;k<32;++k) pin4(w4[k]);   // force residency; budget 256 accommodates ~185
  }
  bool isg = (gate==2);
  float Ac = isg?1.f:0.f, Bc = isg?-2.f:1.f, Sc = isg?2.f:-1.f;

  if(tid<UL) hbuf[0][(tid>>5)*36 + (tid&31)] = 0.0f;
  float c = 0.0f;
  float zc = zin[(size_t)b*HH*GD + tid];
  __syncthreads();

  int cur = 0;
  #pragma unroll 1
  for(int t=0;t<HH;++t){
    float nz = 0.f;
    if(t+1<HH) nz = zin[((size_t)b*HH + t+1)*GD + tid];   // prefetch next step
    const float4* hq = (const float4*)&hbuf[cur][q*36];
    float p0=0.f,p1=0.f,p2=0.f,p3=0.f;
    #pragma unroll
    for(int j=0;j<8;++j){
      float4 hv = hq[j];
      p0 += hv.x*w4[4*j].x + hv.y*w4[4*j+1].x + hv.z*w4[4*j+2].x + hv.w*w4[4*j+3].x;
      p1 += hv.x*w4[4*j].y + hv.y*w4[4*j+1].y + hv.z*w4[4*j+2].y + hv.w*w4[4*j+3].y;
      p2 += hv.x*w4[4*j].z + hv.y*w4[4*j+1].z + hv.z*w4[4*j+2].z + hv.w*w4[4*j+3].z;
      p3 += hv.x*w4[4*j].w + hv.y*w4[4*j+1].w + hv.z*w4[4*j+2].w + hv.w*w4[4*j+3].w;
    }
    // 4-lane transpose-reduce (R3-validated verbatim): lane ends with col = tid
    float send0 = q0 ? p0 : p1;
    float send1 = q0 ? p2 : p3;
    float r0 = __shfl_xor(send0, 1);
    float r1 = __shfl_xor(send1, 1);
    float s0 = (q0 ? p1 : p0) + r0;
    float s1v = (q0 ? p3 : p2) + r1;
    float send2 = q1 ? s0 : s1v;
    float r2 = __shfl_xor(send2, 2);
    float z = zc + (q1 ? s1v : s0) + r2;
    // activation (gates 0,1,3 sigmoid; gate 2 tanh), store [unit][gate]
    float act = Ac + Bc*frcp(1.0f + __expf(Sc*z));
    a_s[u*4 + gate] = act;
    __syncthreads();
    // cell update: redundant in all threads for unit u (R3-validated pattern), one b128 read
    float4 a4 = *(const float4*)&a_s[u*4];
    c = a4.y*c + a4.x*a4.z;
    float th = 1.0f - 2.0f*frcp(1.0f + __expf(2.0f*c));
    float hn = a4.w*th;
    if(tid<UL){
      hbuf[cur^1][(u>>5)*36 + (u&31)] = hn;
      if(writeSeq) oseq[((size_t)b*HH + t)*UL + u] = hn;
      else if(t==HH-1) olast[b*192 + 64 + u] = hn;
    }
    __syncthreads();
    cur ^= 1;
    zc = nz;
  }
}

// ---------------- final dense ----------------
__global__ __launch_bounds__(256) void k_out(const float* __restrict__ feat, const float* __restrict__ wo,
        const float* __restrict__ bo, float* __restrict__ out){
  int idx = blockIdx.x*256 + threadIdx.x;
  if(idx >= BB*24) return;
  int b = idx/24, p = idx - b*24;
  float a0 = bo[p], a1 = 0.f, a2 = 0.f, a3 = 0.f;
  const float* f = feat + b*192;
  for(int k=0;k<192;k+=4){
    a0 += f[k]*wo[k*24+p];
    a1 += f[k+1]*wo[(k+1)*24+p];
    a2 += f[k+2]*wo[(k+2)*24+p];
    a3 += f[k+3]*wo[(k+3)*24+p];
  }
  out[idx] = (a0+a1)+(a2+a3);
}

extern "C" void kernel_launch(void* const* d_in, const int* in_sizes, int n_in,
                              void* d_out, int out_size, void* d_ws, size_t ws_size,
                              hipStream_t stream){
  const float* inp = (const float*)d_in[0];
  const float* adj = (const float*)d_in[1];
  const float* w1  = (const float*)d_in[2];
  const float* b1  = (const float*)d_in[3];
  const float* w2  = (const float*)d_in[4];
  const float* b2  = (const float*)d_in[5];
  const float* wc1 = (const float*)d_in[6];
  const float* bc1 = (const float*)d_in[7];
  const float* wc2 = (const float*)d_in[8];
  const float* bc2 = (const float*)d_in[9];
  const float* k1  = (const float*)d_in[10];
  const float* rk1 = (const float*)d_in[11];
  const float* bl1 = (const float*)d_in[12];
  const float* k2  = (const float*)d_in[13];
  const float* rk2 = (const float*)d_in[14];
  const float* bl2 = (const float*)d_in[15];
  const float* wo  = (const float*)d_in[16];
  const float* bo  = (const float*)d_in[17];
  float* out = (float*)d_out;
  float* ws = (float*)d_ws;

  float* ps   = ws;                 // 524288
  float* nf   = ps + 524288;        // 229376
  float* h1   = nf + 229376;        // 1048576
  float* g    = h1 + 1048576;       // 524288
  float* feat = g  + 524288;        // 12288
  float* l1   = feat + 12288;       // 1376256
  float* zin  = l1 + 1376256;       // 5505024 (shared by zin1 and zin2, sequential use)

  k_sum  <<<dim3(256), dim3(256), 0, stream>>>(inp, ps);
  k_sumc <<<dim3(128), dim3(256), 0, stream>>>(ps, nf);
  k_gcn1 <<<dim3(256), dim3(256), 0, stream>>>(nf, adj, w1, b1, h1);
  k_gcn2 <<<dim3(256), dim3(256), 0, stream>>>(h1, adj, w2, b2, g);
  k_conv <<<dim3(64),  dim3(256), 0, stream>>>(g, wc1, bc1, wc2, bc2, feat);
  k_xk1  <<<dim3(512), dim3(256), 0, stream>>>(inp, k1, bl1, zin);
  k_rec  <<<dim3(64),  dim3(512), 0, stream>>>(zin, rk1, l1, feat, 1);
  k_zin2 <<<dim3(512), dim3(256), 0, stream>>>(l1, k2, bl2, zin);
  k_rec  <<<dim3(64),  dim3(512), 0, stream>>>(zin, rk2, l1, feat, 0);
  k_out  <<<dim3(6),   dim3(256), 0, stream>>>(feat, wo, bo, out);
}